// Round 6
// baseline (810.502 us; speedup 1.0000x reference)
//
#include <hip/hip_runtime.h>
#include <hip/hip_bf16.h>
#include <stdint.h>

// Problem constants (fixed by reference setup)
#define N_NODES 50000
#define M_PAD   50048          // 391 * 128
#define N_EDGES 1600000
#define R_REL   5
#define NSEG    (N_NODES * R_REL)    // 250000
#define SCAN_BLOCKS 245              // ceil(NSEG / 1024)
#define HIST_BLOCKS 196              // ceil(N_NODES / 256)

typedef __bf16 bf16;
typedef __bf16 bf16x2 __attribute__((ext_vector_type(2)));
typedef __bf16 bf16x4 __attribute__((ext_vector_type(4)));
typedef __bf16 bf16x8 __attribute__((ext_vector_type(8)));
typedef float  f32x4  __attribute__((ext_vector_type(4)));

#define GLOAD_LDS16(g, l)                                                          \
    __builtin_amdgcn_global_load_lds(                                              \
        (const __attribute__((address_space(1))) void*)(g),                        \
        (__attribute__((address_space(3))) void*)(l), 16, 0, 0)

// ---------------------------------------------------------------------------
// h0[n,:] = xlist[node_type[n]][local_idx[n], :]  (f32 -> bf16), 4 rows/block
__global__ __launch_bounds__(256) void group_input_k(
    const float* __restrict__ x0, const float* __restrict__ x1,
    const float* __restrict__ emb2, const int* __restrict__ ntype,
    const int* __restrict__ lidx, bf16* __restrict__ h)
{
    int row = blockIdx.x * 4 + (threadIdx.x >> 6);
    int lane = threadIdx.x & 63;
    if (row >= N_NODES) return;
    int t = ntype[row];
    int li = lidx[row];
    const float* src = (t == 0) ? x0 : (t == 1) ? x1 : emb2;
    float4 v = *reinterpret_cast<const float4*>(&src[(size_t)li * 256 + lane * 4]);
    bf16x4 o;
    o[0] = (bf16)v.x; o[1] = (bf16)v.y; o[2] = (bf16)v.z; o[3] = (bf16)v.w;
    *reinterpret_cast<bf16x4*>(&h[(size_t)row * 256 + lane * 4]) = o;
}

// ---------------------------------------------------------------------------
// CSR build: histogram over seg = dst*R + edge_type; rank = position in seg
__global__ __launch_bounds__(256) void hist_k(
    const int* __restrict__ ei, const int* __restrict__ et,
    int* __restrict__ cnt, int* __restrict__ rank)
{
    int e = blockIdx.x * 256 + threadIdx.x;
    if (e >= N_EDGES) return;
    int dst = ei[N_EDGES + e];
    rank[e] = atomicAdd(&cnt[dst * R_REL + et[e]], 1);
}

// Two-level exclusive scan (1024 elems per block)
__global__ __launch_bounds__(256) void scan1_k(
    const int* __restrict__ cnt, int* __restrict__ excl, int* __restrict__ blksum)
{
    __shared__ int lds[256];
    int base = blockIdx.x * 1024;
    int t = threadIdx.x;
    int vals[4]; int s = 0;
#pragma unroll
    for (int i = 0; i < 4; ++i) {
        int idx = base + t * 4 + i;
        vals[i] = (idx < NSEG) ? cnt[idx] : 0;
        s += vals[i];
    }
    lds[t] = s;
    __syncthreads();
    for (int off = 1; off < 256; off <<= 1) {
        int v = (t >= off) ? lds[t - off] : 0;
        __syncthreads();
        lds[t] += v;
        __syncthreads();
    }
    int incl = lds[t];
    int ex = incl - s;
    if (t == 255) blksum[blockIdx.x] = incl;
    int run = ex;
#pragma unroll
    for (int i = 0; i < 4; ++i) {
        int idx = base + t * 4 + i;
        if (idx < NSEG) excl[idx] = run;
        run += vals[i];
    }
}

__global__ __launch_bounds__(256) void scan2_k(int* __restrict__ blksum, int nblk)
{
    __shared__ int lds[256];
    int t = threadIdx.x;
    int v = (t < nblk) ? blksum[t] : 0;
    lds[t] = v;
    __syncthreads();
    for (int off = 1; off < 256; off <<= 1) {
        int u = (t >= off) ? lds[t - off] : 0;
        __syncthreads();
        lds[t] += u;
        __syncthreads();
    }
    if (t < nblk) blksum[t] = lds[t] - v;  // exclusive over block sums
}

// Fold block offsets into excl -> absolute segment starts; add sentinel.
__global__ __launch_bounds__(256) void finalize_k(
    int* __restrict__ excl, const int* __restrict__ blks)
{
    int base = blockIdx.x * 1024 + threadIdx.x * 4;
    int b = blks[blockIdx.x];
#pragma unroll
    for (int i = 0; i < 4; ++i) {
        int idx = base + i;
        if (idx < NSEG) excl[idx] += b;
    }
    if (blockIdx.x == 0 && threadIdx.x == 0) excl[NSEG] = N_EDGES;
}

// Scatter (atomic-free): pos = excl[seg] + rank[e]
__global__ __launch_bounds__(256) void scatter_k(
    const int* __restrict__ ei, const int* __restrict__ et,
    const int* __restrict__ excl, const int* __restrict__ cnt,
    const int* __restrict__ rank, int* __restrict__ sidx, float* __restrict__ wgt)
{
    int e = blockIdx.x * 256 + threadIdx.x;
    if (e >= N_EDGES) return;
    int r = et[e];
    int seg = ei[N_EDGES + e] * R_REL + r;
    int pos = excl[seg] + rank[e];
    sidx[pos] = ei[e] * R_REL + r;
    wgt[pos] = 1.f / (float)cnt[seg];
}

// ---------------------------------------------------------------------------
// Type partition: perm lists node ids sorted by type (stable by block).
__global__ __launch_bounds__(256) void typed_hist_k(
    const int* __restrict__ ntype, int* __restrict__ tcnt)
{
    __shared__ int c[3];
    if (threadIdx.x < 3) c[threadIdx.x] = 0;
    __syncthreads();
    int n = blockIdx.x * 256 + threadIdx.x;
    if (n < N_NODES) atomicAdd(&c[ntype[n]], 1);
    __syncthreads();
    if (threadIdx.x < 3) tcnt[threadIdx.x * HIST_BLOCKS + blockIdx.x] = c[threadIdx.x];
}

// scan over 3*196=588 values ordered (type, block); emit toff + meta
// meta[0..3]=typestart, meta[4..7]=block-chunk offsets, meta[8..10]=type counts
__global__ __launch_bounds__(1024) void typed_scan_k(
    const int* __restrict__ tcnt, int* __restrict__ toff, int* __restrict__ meta)
{
    __shared__ int lds[1024];
    int t = threadIdx.x;
    int v = (t < 3 * HIST_BLOCKS) ? tcnt[t] : 0;
    lds[t] = v;
    __syncthreads();
    for (int off = 1; off < 1024; off <<= 1) {
        int u = (t >= off) ? lds[t - off] : 0;
        __syncthreads();
        lds[t] += u;
        __syncthreads();
    }
    if (t < 3 * HIST_BLOCKS) toff[t] = lds[t] - v;
    if (t == 0) {
        int ts1 = lds[1 * HIST_BLOCKS - 1];
        int ts2 = lds[2 * HIST_BLOCKS - 1];
        int ts3 = lds[3 * HIST_BLOCKS - 1];
        meta[0] = 0; meta[1] = ts1; meta[2] = ts2; meta[3] = ts3;
        int c0 = ts1, c1 = ts2 - ts1, c2 = ts3 - ts2;
        meta[8] = c0; meta[9] = c1; meta[10] = c2;
        int b0 = (c0 + 127) >> 7, b1 = (c1 + 127) >> 7, b2 = (c2 + 127) >> 7;
        meta[4] = 0; meta[5] = b0; meta[6] = b0 + b1; meta[7] = b0 + b1 + b2;
    }
}

__global__ __launch_bounds__(256) void typed_scatter_k(
    const int* __restrict__ ntype, const int* __restrict__ toff,
    int* __restrict__ perm)
{
    __shared__ int cur[3];
    if (threadIdx.x < 3) cur[threadIdx.x] = 0;
    __syncthreads();
    int n = blockIdx.x * 256 + threadIdx.x;
    if (n < N_NODES) {
        int t = ntype[n];
        int rank = atomicAdd(&cur[t], 1);
        perm[toff[t * HIST_BLOCKS + blockIdx.x] + rank] = n;
    }
}

// ---------------------------------------------------------------------------
// Weight prep: Wt arranged [half][r][128][256]: row w = h*640 + r*128 + oo
// maps to relW[r][h*128+oo][:]. Rt = straight cast of rootW.
__global__ __launch_bounds__(256) void cast_w_k(
    const float* __restrict__ relW, const float* __restrict__ rootW,
    bf16* __restrict__ Wt, bf16* __restrict__ Rt, int Dout)
{
    int i = blockIdx.x * 256 + threadIdx.x;
    int relN = R_REL * Dout * 256;
    if (i < relN) {
        int d = i & 255;
        int w = i >> 8;
        int h = w / 640;
        int rem = w - h * 640;
        int r = rem >> 7;
        int o = h * 128 + (rem & 127);
        Wt[i] = (bf16)relW[((size_t)r * Dout + o) * 256 + d];
    }
    int rootN = 3 * Dout * 256;
    if (i < rootN) Rt[i] = (bf16)rootW[i];
}

// ---------------------------------------------------------------------------
// Y GEMM: Y[m, j] = sum_d h[m, d] * W[j, d]   (bf16 out, K=256, no row guard)
__global__ __launch_bounds__(256) void gemm_y_k(
    const bf16* __restrict__ A, const bf16* __restrict__ B,
    bf16* __restrict__ Y, int ldc)
{
    __shared__ bf16 As[128][64];
    __shared__ bf16 Bs[128][64];
    int tid = threadIdx.x;
    int lane = tid & 63, wave = tid >> 6;
    int wm = wave >> 1, wn = wave & 1;
    int m0 = blockIdx.x * 128, n0 = blockIdx.y * 128;

    f32x4 acc[4][4] = {};

    for (int kt = 0; kt < 4; ++kt) {
#pragma unroll
        for (int cc = 0; cc < 4; ++cc) {
            int linear = cc * 256 + tid;
            int row = linear >> 3, sl = linear & 7;
            const bf16* gA = &A[(size_t)(m0 + row) * 256 + kt * 64 + sl * 8];
            const bf16* gB = &B[(size_t)(n0 + row) * 256 + kt * 64 + sl * 8];
            char* sA = (char*)&As[0][0] + (size_t)(cc * 256 + wave * 64) * 16;
            char* sB = (char*)&Bs[0][0] + (size_t)(cc * 256 + wave * 64) * 16;
            GLOAD_LDS16(gA, sA);
            GLOAD_LDS16(gB, sB);
        }
        __syncthreads();
#pragma unroll
        for (int kk = 0; kk < 2; ++kk) {
            bf16x8 af[4], bfr[4];
            int k0 = kk * 32 + (lane >> 4) * 8;
#pragma unroll
            for (int i = 0; i < 4; ++i) {
                af[i]  = *reinterpret_cast<const bf16x8*>(&As[wm * 64 + i * 16 + (lane & 15)][k0]);
                bfr[i] = *reinterpret_cast<const bf16x8*>(&Bs[wn * 64 + i * 16 + (lane & 15)][k0]);
            }
#pragma unroll
            for (int i = 0; i < 4; ++i)
#pragma unroll
                for (int j = 0; j < 4; ++j)
                    acc[i][j] = __builtin_amdgcn_mfma_f32_16x16x32_bf16(af[i], bfr[j], acc[i][j], 0, 0, 0);
        }
        __syncthreads();
    }

#pragma unroll
    for (int i = 0; i < 4; ++i)
#pragma unroll
        for (int j = 0; j < 4; ++j)
#pragma unroll
            for (int r = 0; r < 4; ++r) {
                int row = m0 + wm * 64 + i * 16 + (lane >> 4) * 4 + r;
                int col = n0 + wn * 64 + j * 16 + (lane & 15);
                Y[(size_t)row * ldc + col] = (bf16)acc[i][j][r];
            }
}

// ---------------------------------------------------------------------------
// Gather-accumulate over one 128-wide column slab:
// Cb[n, lane*2..+1] = sum over node n's edges of wgt_e * Y[sidx_e, lane*2..+1]
// Y slab rows are 128 wide (256 B) so the random-read working set is 64 MB.
__global__ __launch_bounds__(256) void gather_k(
    const bf16* __restrict__ Y, const int* __restrict__ sidx,
    const float* __restrict__ wgt, const int* __restrict__ excl,
    bf16* __restrict__ Cb, int ldcb)
{
    int wave = threadIdx.x >> 6, lane = threadIdx.x & 63;
    int n = blockIdx.x * 4 + wave;
    if (n >= N_NODES) return;
    int off0 = excl[n * R_REL];
    int off1 = excl[n * R_REL + R_REL];
    int c = off1 - off0;

    float s0 = 0.f, s1 = 0.f;
    int e = 0;
    for (; e + 8 <= c; e += 8) {
        int ix[8]; float ww[8]; bf16x2 v[8];
#pragma unroll
        for (int j = 0; j < 8; ++j) ix[j] = sidx[off0 + e + j];
#pragma unroll
        for (int j = 0; j < 8; ++j) ww[j] = wgt[off0 + e + j];
#pragma unroll
        for (int j = 0; j < 8; ++j)
            v[j] = *reinterpret_cast<const bf16x2*>(&Y[(size_t)ix[j] * 128 + lane * 2]);
#pragma unroll
        for (int j = 0; j < 8; ++j) {
            s0 += ww[j] * (float)v[j][0];
            s1 += ww[j] * (float)v[j][1];
        }
    }
    if (e + 4 <= c) {
        int ix[4]; float ww[4]; bf16x2 v[4];
#pragma unroll
        for (int j = 0; j < 4; ++j) ix[j] = sidx[off0 + e + j];
#pragma unroll
        for (int j = 0; j < 4; ++j) ww[j] = wgt[off0 + e + j];
#pragma unroll
        for (int j = 0; j < 4; ++j)
            v[j] = *reinterpret_cast<const bf16x2*>(&Y[(size_t)ix[j] * 128 + lane * 2]);
#pragma unroll
        for (int j = 0; j < 4; ++j) {
            s0 += ww[j] * (float)v[j][0];
            s1 += ww[j] * (float)v[j][1];
        }
        e += 4;
    }
    for (; e < c; ++e) {
        int ix = sidx[off0 + e]; float ww = wgt[off0 + e];
        bf16x2 v = *reinterpret_cast<const bf16x2*>(&Y[(size_t)ix * 128 + lane * 2]);
        s0 += ww * (float)v[0];
        s1 += ww * (float)v[1];
    }

    bf16x2 o; o[0] = (bf16)s0; o[1] = (bf16)s1;
    *reinterpret_cast<bf16x2*>(&Cb[(size_t)n * ldcb + lane * 2]) = o;
}

// ---------------------------------------------------------------------------
// Root GEMM over type-sorted 128-row chunks: out = Cb[ri] + h[ri]@Rt[t]^T + b[t]
// relu_mode: ReLU + bf16 emit to hout; else fp32 emit to C (last layer).
__global__ __launch_bounds__(256) void gemm_root_k(
    const bf16* __restrict__ h, const bf16* __restrict__ Rt,
    const float* __restrict__ rootB, const int* __restrict__ perm,
    const int* __restrict__ meta, const bf16* __restrict__ Cb,
    float* __restrict__ C, bf16* __restrict__ hout, int Dout, int relu_mode)
{
    __shared__ bf16 As[128][64];
    __shared__ bf16 Bs[128][64];
    __shared__ int ridx[128];
    int tid = threadIdx.x;
    int bx = blockIdx.x;
    int b1 = meta[5], b2 = meta[6], b3 = meta[7];
    if (bx >= b3) return;
    int t = (bx >= b2) ? 2 : (bx >= b1 ? 1 : 0);
    int chunk = bx - (t == 2 ? b2 : (t == 1 ? b1 : 0));
    int tstart = meta[t];
    int tc = meta[8 + t];
    int rbase = chunk * 128;
    if (tid < 128) {
        int lr = rbase + tid;
        ridx[tid] = (lr < tc) ? perm[tstart + lr] : 0;
    }
    __syncthreads();

    int lane = tid & 63, wave = tid >> 6;
    int wm = wave >> 1, wn = wave & 1;
    int n0 = blockIdx.y * 128;
    const bf16* B = Rt + (size_t)t * Dout * 256;

    f32x4 acc[4][4] = {};

    for (int kt = 0; kt < 4; ++kt) {   // K = 256
#pragma unroll
        for (int cc = 0; cc < 4; ++cc) {
            int linear = cc * 256 + tid;
            int row = linear >> 3, sl = linear & 7;
            const bf16* gA = &h[(size_t)ridx[row] * 256 + kt * 64 + sl * 8];
            const bf16* gB = &B[(size_t)(n0 + row) * 256 + kt * 64 + sl * 8];
            char* sA = (char*)&As[0][0] + (size_t)(cc * 256 + wave * 64) * 16;
            char* sB = (char*)&Bs[0][0] + (size_t)(cc * 256 + wave * 64) * 16;
            GLOAD_LDS16(gA, sA);
            GLOAD_LDS16(gB, sB);
        }
        __syncthreads();
#pragma unroll
        for (int kk = 0; kk < 2; ++kk) {
            bf16x8 af[4], bfr[4];
            int k0 = kk * 32 + (lane >> 4) * 8;
#pragma unroll
            for (int i = 0; i < 4; ++i) {
                af[i]  = *reinterpret_cast<const bf16x8*>(&As[wm * 64 + i * 16 + (lane & 15)][k0]);
                bfr[i] = *reinterpret_cast<const bf16x8*>(&Bs[wn * 64 + i * 16 + (lane & 15)][k0]);
            }
#pragma unroll
            for (int i = 0; i < 4; ++i)
#pragma unroll
                for (int j = 0; j < 4; ++j)
                    acc[i][j] = __builtin_amdgcn_mfma_f32_16x16x32_bf16(af[i], bfr[j], acc[i][j], 0, 0, 0);
        }
        __syncthreads();
    }

#pragma unroll
    for (int i = 0; i < 4; ++i)
#pragma unroll
        for (int j = 0; j < 4; ++j)
#pragma unroll
            for (int r = 0; r < 4; ++r) {
                int rl = wm * 64 + i * 16 + (lane >> 4) * 4 + r;
                int col = n0 + wn * 64 + j * 16 + (lane & 15);
                if (rbase + rl < tc) {
                    int ri = ridx[rl];
                    float v = (float)Cb[(size_t)ri * Dout + col] + acc[i][j][r]
                              + rootB[t * Dout + col];
                    if (relu_mode)
                        hout[(size_t)ri * Dout + col] = (bf16)fmaxf(v, 0.f);
                    else
                        C[(size_t)ri * Dout + col] = v;
                }
            }
}

// ---------------------------------------------------------------------------
// Row-wise log_softmax over 128 logits; one wave per row.
__global__ __launch_bounds__(256) void logsoftmax_k(
    const float* __restrict__ C, float* __restrict__ out, int M)
{
    int row = blockIdx.x * 4 + (threadIdx.x >> 6);
    int lane = threadIdx.x & 63;
    if (row >= M) return;
    float v0 = C[(size_t)row * 128 + lane];
    float v1 = C[(size_t)row * 128 + 64 + lane];
    float m = fmaxf(v0, v1);
    for (int off = 32; off; off >>= 1) m = fmaxf(m, __shfl_xor(m, off));
    float s = expf(v0 - m) + expf(v1 - m);
    for (int off = 32; off; off >>= 1) s += __shfl_xor(s, off);
    float lse = m + logf(s);
    out[(size_t)row * 128 + lane] = v0 - lse;
    out[(size_t)row * 128 + 64 + lane] = v1 - lse;
}

// ---------------------------------------------------------------------------
extern "C" void kernel_launch(void* const* d_in, const int* in_sizes, int n_in,
                              void* d_out, int out_size, void* d_ws, size_t ws_size,
                              hipStream_t stream)
{
    const float* x0   = (const float*)d_in[0];
    const float* x1   = (const float*)d_in[1];
    const float* emb2 = (const float*)d_in[2];
    const int*   ei   = (const int*)d_in[3];
    const int*   et   = (const int*)d_in[4];
    const int*   ntyp = (const int*)d_in[5];
    const int*   lidx = (const int*)d_in[6];
    const float* relW[3]  = {(const float*)d_in[7],  (const float*)d_in[10], (const float*)d_in[13]};
    const float* rootW[3] = {(const float*)d_in[8],  (const float*)d_in[11], (const float*)d_in[14]};
    const float* rootB[3] = {(const float*)d_in[9],  (const float*)d_in[12], (const float*)d_in[15]};
    float* out = (float*)d_out;

    char* p = (char*)d_ws;
    auto carve = [&](size_t bytes) {
        char* q = p;
        p += (bytes + 255) & ~(size_t)255;
        return (void*)q;
    };
    bf16* h_a   = (bf16*)carve((size_t)M_PAD * 256 * 2);
    bf16* h_b   = (bf16*)carve((size_t)M_PAD * 256 * 2);
    bf16* Y     = (bf16*)carve((size_t)2 * M_PAD * 640 * 2);  // two 64 MB slabs
    bf16* Cb    = (bf16*)carve((size_t)M_PAD * 256 * 2);
    bf16* Wt    = (bf16*)carve((size_t)R_REL * 256 * 256 * 2);
    bf16* Rt    = (bf16*)carve((size_t)3 * 256 * 256 * 2);
    int* cnt    = (int*)carve((size_t)NSEG * 4);
    int* excl   = (int*)carve((size_t)(NSEG + 1) * 4);
    int* blks   = (int*)carve((size_t)256 * 4);
    int* rank   = (int*)carve((size_t)N_EDGES * 4);
    int* sidx   = (int*)carve((size_t)N_EDGES * 4);
    float* wgt  = (float*)carve((size_t)N_EDGES * 4);
    int* tcnt   = (int*)carve((size_t)3 * HIST_BLOCKS * 4);
    int* toff   = (int*)carve((size_t)3 * HIST_BLOCKS * 4);
    int* meta   = (int*)carve((size_t)16 * 4);
    int* perm   = (int*)carve((size_t)N_NODES * 4);
    // fp32 logits buffer aliased into Y slab 1 (dead by layer 3, which uses
    // only slab 0 = 64.06 MB; C sits at +96 MB, needs 25.6 MB < 128.1 MB).
    float* C = (float*)((char*)Y + (size_t)96 * 1024 * 1024);

    hipMemsetAsync(cnt, 0, (size_t)NSEG * 4, stream);

    group_input_k<<<(N_NODES + 3) / 4, 256, 0, stream>>>(x0, x1, emb2, ntyp, lidx, h_a);
    hist_k<<<(N_EDGES + 255) / 256, 256, 0, stream>>>(ei, et, cnt, rank);
    scan1_k<<<SCAN_BLOCKS, 256, 0, stream>>>(cnt, excl, blks);
    scan2_k<<<1, 256, 0, stream>>>(blks, SCAN_BLOCKS);
    finalize_k<<<SCAN_BLOCKS, 256, 0, stream>>>(excl, blks);
    scatter_k<<<(N_EDGES + 255) / 256, 256, 0, stream>>>(ei, et, excl, cnt, rank, sidx, wgt);
    typed_hist_k<<<HIST_BLOCKS, 256, 0, stream>>>(ntyp, tcnt);
    typed_scan_k<<<1, 1024, 0, stream>>>(tcnt, toff, meta);
    typed_scatter_k<<<HIST_BLOCKS, 256, 0, stream>>>(ntyp, toff, perm);

    bf16* cur = h_a;
    bf16* nxt = h_b;
    const int douts[3] = {256, 256, 128};
    for (int l = 0; l < 3; ++l) {
        int Dout = douts[l];
        int NH = Dout / 128;
        cast_w_k<<<(R_REL * Dout * 256 + 255) / 256, 256, 0, stream>>>(
            relW[l], rootW[l], Wt, Rt, Dout);
        for (int h = 0; h < NH; ++h) {
            bf16* Yh = Y + (size_t)h * M_PAD * 640;
            gemm_y_k<<<dim3(M_PAD / 128, 5), 256, 0, stream>>>(
                cur, Wt + (size_t)h * 640 * 256, Yh, 640);
            gather_k<<<(N_NODES + 3) / 4, 256, 0, stream>>>(
                Yh, sidx, wgt, excl, Cb + h * 128, Dout);
        }
        gemm_root_k<<<dim3(393, Dout / 128), 256, 0, stream>>>(
            cur, Rt, rootB[l], perm, meta, Cb, C, nxt, Dout, (l < 2) ? 1 : 0);
        bf16* tmp = cur; cur = nxt; nxt = tmp;
    }
    logsoftmax_k<<<(N_NODES + 3) / 4, 256, 0, stream>>>(C, out, N_NODES);
}

// Round 7
// 764.861 us; speedup vs baseline: 1.0597x; 1.0597x over previous
//
#include <hip/hip_runtime.h>
#include <hip/hip_bf16.h>
#include <stdint.h>

// Problem constants (fixed by reference setup)
#define N_NODES 50000
#define M_PAD   50048          // 391 * 128
#define N_EDGES 1600000
#define R_REL   5
#define NSEG    (N_NODES * R_REL)    // 250000
#define SCAN_BLOCKS 245              // ceil(NSEG / 1024)
#define HIST_BLOCKS 196              // ceil(N_NODES / 256)

typedef __bf16 bf16;
typedef __bf16 bf16x2 __attribute__((ext_vector_type(2)));
typedef __bf16 bf16x4 __attribute__((ext_vector_type(4)));
typedef __bf16 bf16x8 __attribute__((ext_vector_type(8)));
typedef float  f32x4  __attribute__((ext_vector_type(4)));

#define GLOAD_LDS16(g, l)                                                          \
    __builtin_amdgcn_global_load_lds(                                              \
        (const __attribute__((address_space(1))) void*)(g),                        \
        (__attribute__((address_space(3))) void*)(l), 16, 0, 0)

// ---------------------------------------------------------------------------
// h0[n,:] = xlist[node_type[n]][local_idx[n], :]  (f32 -> bf16), 4 rows/block
__global__ __launch_bounds__(256) void group_input_k(
    const float* __restrict__ x0, const float* __restrict__ x1,
    const float* __restrict__ emb2, const int* __restrict__ ntype,
    const int* __restrict__ lidx, bf16* __restrict__ h)
{
    int row = blockIdx.x * 4 + (threadIdx.x >> 6);
    int lane = threadIdx.x & 63;
    if (row >= N_NODES) return;
    int t = ntype[row];
    int li = lidx[row];
    const float* src = (t == 0) ? x0 : (t == 1) ? x1 : emb2;
    float4 v = *reinterpret_cast<const float4*>(&src[(size_t)li * 256 + lane * 4]);
    bf16x4 o;
    o[0] = (bf16)v.x; o[1] = (bf16)v.y; o[2] = (bf16)v.z; o[3] = (bf16)v.w;
    *reinterpret_cast<bf16x4*>(&h[(size_t)row * 256 + lane * 4]) = o;
}

// ---------------------------------------------------------------------------
// CSR build: histogram over seg = dst*R + edge_type; rank = position in seg
__global__ __launch_bounds__(256) void hist_k(
    const int* __restrict__ ei, const int* __restrict__ et,
    int* __restrict__ cnt, int* __restrict__ rank)
{
    int e = blockIdx.x * 256 + threadIdx.x;
    if (e >= N_EDGES) return;
    int dst = ei[N_EDGES + e];
    rank[e] = atomicAdd(&cnt[dst * R_REL + et[e]], 1);
}

// Two-level exclusive scan (1024 elems per block)
__global__ __launch_bounds__(256) void scan1_k(
    const int* __restrict__ cnt, int* __restrict__ excl, int* __restrict__ blksum)
{
    __shared__ int lds[256];
    int base = blockIdx.x * 1024;
    int t = threadIdx.x;
    int vals[4]; int s = 0;
#pragma unroll
    for (int i = 0; i < 4; ++i) {
        int idx = base + t * 4 + i;
        vals[i] = (idx < NSEG) ? cnt[idx] : 0;
        s += vals[i];
    }
    lds[t] = s;
    __syncthreads();
    for (int off = 1; off < 256; off <<= 1) {
        int v = (t >= off) ? lds[t - off] : 0;
        __syncthreads();
        lds[t] += v;
        __syncthreads();
    }
    int incl = lds[t];
    int ex = incl - s;
    if (t == 255) blksum[blockIdx.x] = incl;
    int run = ex;
#pragma unroll
    for (int i = 0; i < 4; ++i) {
        int idx = base + t * 4 + i;
        if (idx < NSEG) excl[idx] = run;
        run += vals[i];
    }
}

__global__ __launch_bounds__(256) void scan2_k(int* __restrict__ blksum, int nblk)
{
    __shared__ int lds[256];
    int t = threadIdx.x;
    int v = (t < nblk) ? blksum[t] : 0;
    lds[t] = v;
    __syncthreads();
    for (int off = 1; off < 256; off <<= 1) {
        int u = (t >= off) ? lds[t - off] : 0;
        __syncthreads();
        lds[t] += u;
        __syncthreads();
    }
    if (t < nblk) blksum[t] = lds[t] - v;  // exclusive over block sums
}

// Fold block offsets into excl -> absolute segment starts; add sentinel.
__global__ __launch_bounds__(256) void finalize_k(
    int* __restrict__ excl, const int* __restrict__ blks)
{
    int base = blockIdx.x * 1024 + threadIdx.x * 4;
    int b = blks[blockIdx.x];
#pragma unroll
    for (int i = 0; i < 4; ++i) {
        int idx = base + i;
        if (idx < NSEG) excl[idx] += b;
    }
    if (blockIdx.x == 0 && threadIdx.x == 0) excl[NSEG] = N_EDGES;
}

// Scatter (atomic-free, single 4B store per edge):
// pk[pos] = (src*R + r) | cnt(seg) << 18   (idx < 2^18, cnt < 2^14)
__global__ __launch_bounds__(256) void scatter_k(
    const int* __restrict__ ei, const int* __restrict__ et,
    const int* __restrict__ excl, const int* __restrict__ cnt,
    const int* __restrict__ rank, uint32_t* __restrict__ pk)
{
    int e = blockIdx.x * 256 + threadIdx.x;
    if (e >= N_EDGES) return;
    int r = et[e];
    int seg = ei[N_EDGES + e] * R_REL + r;
    int pos = excl[seg] + rank[e];
    pk[pos] = (uint32_t)(ei[e] * R_REL + r) | ((uint32_t)cnt[seg] << 18);
}

// ---------------------------------------------------------------------------
// Type partition: perm lists node ids sorted by type (stable by block).
__global__ __launch_bounds__(256) void typed_hist_k(
    const int* __restrict__ ntype, int* __restrict__ tcnt)
{
    __shared__ int c[3];
    if (threadIdx.x < 3) c[threadIdx.x] = 0;
    __syncthreads();
    int n = blockIdx.x * 256 + threadIdx.x;
    if (n < N_NODES) atomicAdd(&c[ntype[n]], 1);
    __syncthreads();
    if (threadIdx.x < 3) tcnt[threadIdx.x * HIST_BLOCKS + blockIdx.x] = c[threadIdx.x];
}

// scan over 3*196=588 values ordered (type, block); emit toff + meta
// meta[0..3]=typestart, meta[4..7]=block-chunk offsets, meta[8..10]=type counts
__global__ __launch_bounds__(1024) void typed_scan_k(
    const int* __restrict__ tcnt, int* __restrict__ toff, int* __restrict__ meta)
{
    __shared__ int lds[1024];
    int t = threadIdx.x;
    int v = (t < 3 * HIST_BLOCKS) ? tcnt[t] : 0;
    lds[t] = v;
    __syncthreads();
    for (int off = 1; off < 1024; off <<= 1) {
        int u = (t >= off) ? lds[t - off] : 0;
        __syncthreads();
        lds[t] += u;
        __syncthreads();
    }
    if (t < 3 * HIST_BLOCKS) toff[t] = lds[t] - v;
    if (t == 0) {
        int ts1 = lds[1 * HIST_BLOCKS - 1];
        int ts2 = lds[2 * HIST_BLOCKS - 1];
        int ts3 = lds[3 * HIST_BLOCKS - 1];
        meta[0] = 0; meta[1] = ts1; meta[2] = ts2; meta[3] = ts3;
        int c0 = ts1, c1 = ts2 - ts1, c2 = ts3 - ts2;
        meta[8] = c0; meta[9] = c1; meta[10] = c2;
        int b0 = (c0 + 127) >> 7, b1 = (c1 + 127) >> 7, b2 = (c2 + 127) >> 7;
        meta[4] = 0; meta[5] = b0; meta[6] = b0 + b1; meta[7] = b0 + b1 + b2;
    }
}

__global__ __launch_bounds__(256) void typed_scatter_k(
    const int* __restrict__ ntype, const int* __restrict__ toff,
    int* __restrict__ perm)
{
    __shared__ int cur[3];
    if (threadIdx.x < 3) cur[threadIdx.x] = 0;
    __syncthreads();
    int n = blockIdx.x * 256 + threadIdx.x;
    if (n < N_NODES) {
        int t = ntype[n];
        int rank = atomicAdd(&cur[t], 1);
        perm[toff[t * HIST_BLOCKS + blockIdx.x] + rank] = n;
    }
}

// ---------------------------------------------------------------------------
// Weight prep: Wt arranged [half][r][128][256]: row w = h*640 + r*128 + oo
// maps to relW[r][h*128+oo][:]. Rt = straight cast of rootW.
__global__ __launch_bounds__(256) void cast_w_k(
    const float* __restrict__ relW, const float* __restrict__ rootW,
    bf16* __restrict__ Wt, bf16* __restrict__ Rt, int Dout)
{
    int i = blockIdx.x * 256 + threadIdx.x;
    int relN = R_REL * Dout * 256;
    if (i < relN) {
        int d = i & 255;
        int w = i >> 8;
        int h = w / 640;
        int rem = w - h * 640;
        int r = rem >> 7;
        int o = h * 128 + (rem & 127);
        Wt[i] = (bf16)relW[((size_t)r * Dout + o) * 256 + d];
    }
    int rootN = 3 * Dout * 256;
    if (i < rootN) Rt[i] = (bf16)rootW[i];
}

// ---------------------------------------------------------------------------
// Y GEMM: Y[m, j] = sum_d h[m, d] * W[j, d]   (bf16 out, K=256, no row guard)
__global__ __launch_bounds__(256) void gemm_y_k(
    const bf16* __restrict__ A, const bf16* __restrict__ B,
    bf16* __restrict__ Y, int ldc)
{
    __shared__ bf16 As[128][64];
    __shared__ bf16 Bs[128][64];
    int tid = threadIdx.x;
    int lane = tid & 63, wave = tid >> 6;
    int wm = wave >> 1, wn = wave & 1;
    int m0 = blockIdx.x * 128, n0 = blockIdx.y * 128;

    f32x4 acc[4][4] = {};

    for (int kt = 0; kt < 4; ++kt) {
#pragma unroll
        for (int cc = 0; cc < 4; ++cc) {
            int linear = cc * 256 + tid;
            int row = linear >> 3, sl = linear & 7;
            const bf16* gA = &A[(size_t)(m0 + row) * 256 + kt * 64 + sl * 8];
            const bf16* gB = &B[(size_t)(n0 + row) * 256 + kt * 64 + sl * 8];
            char* sA = (char*)&As[0][0] + (size_t)(cc * 256 + wave * 64) * 16;
            char* sB = (char*)&Bs[0][0] + (size_t)(cc * 256 + wave * 64) * 16;
            GLOAD_LDS16(gA, sA);
            GLOAD_LDS16(gB, sB);
        }
        __syncthreads();
#pragma unroll
        for (int kk = 0; kk < 2; ++kk) {
            bf16x8 af[4], bfr[4];
            int k0 = kk * 32 + (lane >> 4) * 8;
#pragma unroll
            for (int i = 0; i < 4; ++i) {
                af[i]  = *reinterpret_cast<const bf16x8*>(&As[wm * 64 + i * 16 + (lane & 15)][k0]);
                bfr[i] = *reinterpret_cast<const bf16x8*>(&Bs[wn * 64 + i * 16 + (lane & 15)][k0]);
            }
#pragma unroll
            for (int i = 0; i < 4; ++i)
#pragma unroll
                for (int j = 0; j < 4; ++j)
                    acc[i][j] = __builtin_amdgcn_mfma_f32_16x16x32_bf16(af[i], bfr[j], acc[i][j], 0, 0, 0);
        }
        __syncthreads();
    }

#pragma unroll
    for (int i = 0; i < 4; ++i)
#pragma unroll
        for (int j = 0; j < 4; ++j)
#pragma unroll
            for (int r = 0; r < 4; ++r) {
                int row = m0 + wm * 64 + i * 16 + (lane >> 4) * 4 + r;
                int col = n0 + wn * 64 + j * 16 + (lane & 15);
                Y[(size_t)row * ldc + col] = (bf16)acc[i][j][r];
            }
}

// ---------------------------------------------------------------------------
// Gather-accumulate over one 128-wide column slab:
// Cb[n, lane*2..+1] = sum_e (1/cnt_e) * Y[idx_e, lane*2..+1]
// pk packs idx (18b) | cnt (14b); weight via v_rcp_f32 (1 ulp).
__global__ __launch_bounds__(256) void gather_k(
    const bf16* __restrict__ Y, const uint32_t* __restrict__ pk,
    const int* __restrict__ excl, bf16* __restrict__ Cb, int ldcb)
{
    int wave = threadIdx.x >> 6, lane = threadIdx.x & 63;
    int n = blockIdx.x * 4 + wave;
    if (n >= N_NODES) return;
    int off0 = excl[n * R_REL];
    int off1 = excl[n * R_REL + R_REL];
    int c = off1 - off0;

    float s0 = 0.f, s1 = 0.f;
    int e = 0;
    for (; e + 8 <= c; e += 8) {
        uint32_t w[8]; bf16x2 v[8];
#pragma unroll
        for (int j = 0; j < 8; ++j) w[j] = pk[off0 + e + j];
#pragma unroll
        for (int j = 0; j < 8; ++j)
            v[j] = *reinterpret_cast<const bf16x2*>(&Y[(size_t)(w[j] & 0x3FFFF) * 128 + lane * 2]);
#pragma unroll
        for (int j = 0; j < 8; ++j) {
            float ww = __builtin_amdgcn_rcpf((float)(w[j] >> 18));
            s0 += ww * (float)v[j][0];
            s1 += ww * (float)v[j][1];
        }
    }
    if (e + 4 <= c) {
        uint32_t w[4]; bf16x2 v[4];
#pragma unroll
        for (int j = 0; j < 4; ++j) w[j] = pk[off0 + e + j];
#pragma unroll
        for (int j = 0; j < 4; ++j)
            v[j] = *reinterpret_cast<const bf16x2*>(&Y[(size_t)(w[j] & 0x3FFFF) * 128 + lane * 2]);
#pragma unroll
        for (int j = 0; j < 4; ++j) {
            float ww = __builtin_amdgcn_rcpf((float)(w[j] >> 18));
            s0 += ww * (float)v[j][0];
            s1 += ww * (float)v[j][1];
        }
        e += 4;
    }
    for (; e < c; ++e) {
        uint32_t w = pk[off0 + e];
        bf16x2 v = *reinterpret_cast<const bf16x2*>(&Y[(size_t)(w & 0x3FFFF) * 128 + lane * 2]);
        float ww = __builtin_amdgcn_rcpf((float)(w >> 18));
        s0 += ww * (float)v[0];
        s1 += ww * (float)v[1];
    }

    bf16x2 o; o[0] = (bf16)s0; o[1] = (bf16)s1;
    *reinterpret_cast<bf16x2*>(&Cb[(size_t)n * ldcb + lane * 2]) = o;
}

// ---------------------------------------------------------------------------
// Root GEMM over type-sorted 128-row chunks: out = Cb[ri] + h[ri]@Rt[t]^T + b[t]
// relu_mode: ReLU + bf16 emit to hout; else fp32 emit to C (last layer).
__global__ __launch_bounds__(256) void gemm_root_k(
    const bf16* __restrict__ h, const bf16* __restrict__ Rt,
    const float* __restrict__ rootB, const int* __restrict__ perm,
    const int* __restrict__ meta, const bf16* __restrict__ Cb,
    float* __restrict__ C, bf16* __restrict__ hout, int Dout, int relu_mode)
{
    __shared__ bf16 As[128][64];
    __shared__ bf16 Bs[128][64];
    __shared__ int ridx[128];
    int tid = threadIdx.x;
    int bx = blockIdx.x;
    int b1 = meta[5], b2 = meta[6], b3 = meta[7];
    if (bx >= b3) return;
    int t = (bx >= b2) ? 2 : (bx >= b1 ? 1 : 0);
    int chunk = bx - (t == 2 ? b2 : (t == 1 ? b1 : 0));
    int tstart = meta[t];
    int tc = meta[8 + t];
    int rbase = chunk * 128;
    if (tid < 128) {
        int lr = rbase + tid;
        ridx[tid] = (lr < tc) ? perm[tstart + lr] : 0;
    }
    __syncthreads();

    int lane = tid & 63, wave = tid >> 6;
    int wm = wave >> 1, wn = wave & 1;
    int n0 = blockIdx.y * 128;
    const bf16* B = Rt + (size_t)t * Dout * 256;

    f32x4 acc[4][4] = {};

    for (int kt = 0; kt < 4; ++kt) {   // K = 256
#pragma unroll
        for (int cc = 0; cc < 4; ++cc) {
            int linear = cc * 256 + tid;
            int row = linear >> 3, sl = linear & 7;
            const bf16* gA = &h[(size_t)ridx[row] * 256 + kt * 64 + sl * 8];
            const bf16* gB = &B[(size_t)(n0 + row) * 256 + kt * 64 + sl * 8];
            char* sA = (char*)&As[0][0] + (size_t)(cc * 256 + wave * 64) * 16;
            char* sB = (char*)&Bs[0][0] + (size_t)(cc * 256 + wave * 64) * 16;
            GLOAD_LDS16(gA, sA);
            GLOAD_LDS16(gB, sB);
        }
        __syncthreads();
#pragma unroll
        for (int kk = 0; kk < 2; ++kk) {
            bf16x8 af[4], bfr[4];
            int k0 = kk * 32 + (lane >> 4) * 8;
#pragma unroll
            for (int i = 0; i < 4; ++i) {
                af[i]  = *reinterpret_cast<const bf16x8*>(&As[wm * 64 + i * 16 + (lane & 15)][k0]);
                bfr[i] = *reinterpret_cast<const bf16x8*>(&Bs[wn * 64 + i * 16 + (lane & 15)][k0]);
            }
#pragma unroll
            for (int i = 0; i < 4; ++i)
#pragma unroll
                for (int j = 0; j < 4; ++j)
                    acc[i][j] = __builtin_amdgcn_mfma_f32_16x16x32_bf16(af[i], bfr[j], acc[i][j], 0, 0, 0);
        }
        __syncthreads();
    }

#pragma unroll
    for (int i = 0; i < 4; ++i)
#pragma unroll
        for (int j = 0; j < 4; ++j)
#pragma unroll
            for (int r = 0; r < 4; ++r) {
                int rl = wm * 64 + i * 16 + (lane >> 4) * 4 + r;
                int col = n0 + wn * 64 + j * 16 + (lane & 15);
                if (rbase + rl < tc) {
                    int ri = ridx[rl];
                    float v = (float)Cb[(size_t)ri * Dout + col] + acc[i][j][r]
                              + rootB[t * Dout + col];
                    if (relu_mode)
                        hout[(size_t)ri * Dout + col] = (bf16)fmaxf(v, 0.f);
                    else
                        C[(size_t)ri * Dout + col] = v;
                }
            }
}

// ---------------------------------------------------------------------------
// Row-wise log_softmax over 128 logits; one wave per row.
__global__ __launch_bounds__(256) void logsoftmax_k(
    const float* __restrict__ C, float* __restrict__ out, int M)
{
    int row = blockIdx.x * 4 + (threadIdx.x >> 6);
    int lane = threadIdx.x & 63;
    if (row >= M) return;
    float v0 = C[(size_t)row * 128 + lane];
    float v1 = C[(size_t)row * 128 + 64 + lane];
    float m = fmaxf(v0, v1);
    for (int off = 32; off; off >>= 1) m = fmaxf(m, __shfl_xor(m, off));
    float s = expf(v0 - m) + expf(v1 - m);
    for (int off = 32; off; off >>= 1) s += __shfl_xor(s, off);
    float lse = m + logf(s);
    out[(size_t)row * 128 + lane] = v0 - lse;
    out[(size_t)row * 128 + 64 + lane] = v1 - lse;
}

// ---------------------------------------------------------------------------
extern "C" void kernel_launch(void* const* d_in, const int* in_sizes, int n_in,
                              void* d_out, int out_size, void* d_ws, size_t ws_size,
                              hipStream_t stream)
{
    const float* x0   = (const float*)d_in[0];
    const float* x1   = (const float*)d_in[1];
    const float* emb2 = (const float*)d_in[2];
    const int*   ei   = (const int*)d_in[3];
    const int*   et   = (const int*)d_in[4];
    const int*   ntyp = (const int*)d_in[5];
    const int*   lidx = (const int*)d_in[6];
    const float* relW[3]  = {(const float*)d_in[7],  (const float*)d_in[10], (const float*)d_in[13]};
    const float* rootW[3] = {(const float*)d_in[8],  (const float*)d_in[11], (const float*)d_in[14]};
    const float* rootB[3] = {(const float*)d_in[9],  (const float*)d_in[12], (const float*)d_in[15]};
    float* out = (float*)d_out;

    char* p = (char*)d_ws;
    auto carve = [&](size_t bytes) {
        char* q = p;
        p += (bytes + 255) & ~(size_t)255;
        return (void*)q;
    };
    bf16* h_a   = (bf16*)carve((size_t)M_PAD * 256 * 2);
    bf16* h_b   = (bf16*)carve((size_t)M_PAD * 256 * 2);
    bf16* Y     = (bf16*)carve((size_t)2 * M_PAD * 640 * 2);  // two 64 MB slabs
    bf16* Cb    = (bf16*)carve((size_t)M_PAD * 256 * 2);
    bf16* WtA   = (bf16*)carve((size_t)(2 * R_REL * 256 * 256 + R_REL * 128 * 256) * 2);
    bf16* RtA   = (bf16*)carve((size_t)(2 * 3 * 256 * 256 + 3 * 128 * 256) * 2);
    int* cnt    = (int*)carve((size_t)NSEG * 4);
    int* excl   = (int*)carve((size_t)(NSEG + 1) * 4);
    int* blks   = (int*)carve((size_t)256 * 4);
    int* rank   = (int*)carve((size_t)N_EDGES * 4);
    uint32_t* pk = (uint32_t*)carve((size_t)N_EDGES * 4);
    int* tcnt   = (int*)carve((size_t)3 * HIST_BLOCKS * 4);
    int* toff   = (int*)carve((size_t)3 * HIST_BLOCKS * 4);
    int* meta   = (int*)carve((size_t)16 * 4);
    int* perm   = (int*)carve((size_t)N_NODES * 4);
    // fp32 logits buffer aliased into Y slab 1 (dead at layer 3, which uses
    // only slab 0 = 64.06 MB; C sits at +96 MB, needs 25.6 MB < 128.1 MB).
    float* C = (float*)((char*)Y + (size_t)96 * 1024 * 1024);

    bf16* Wt[3] = {WtA, WtA + (size_t)R_REL * 256 * 256, WtA + (size_t)2 * R_REL * 256 * 256};
    bf16* Rt[3] = {RtA, RtA + (size_t)3 * 256 * 256, RtA + (size_t)2 * 3 * 256 * 256};

    hipMemsetAsync(cnt, 0, (size_t)NSEG * 4, stream);

    group_input_k<<<(N_NODES + 3) / 4, 256, 0, stream>>>(x0, x1, emb2, ntyp, lidx, h_a);
    hist_k<<<(N_EDGES + 255) / 256, 256, 0, stream>>>(ei, et, cnt, rank);
    scan1_k<<<SCAN_BLOCKS, 256, 0, stream>>>(cnt, excl, blks);
    scan2_k<<<1, 256, 0, stream>>>(blks, SCAN_BLOCKS);
    finalize_k<<<SCAN_BLOCKS, 256, 0, stream>>>(excl, blks);
    scatter_k<<<(N_EDGES + 255) / 256, 256, 0, stream>>>(ei, et, excl, cnt, rank, pk);
    typed_hist_k<<<HIST_BLOCKS, 256, 0, stream>>>(ntyp, tcnt);
    typed_scan_k<<<1, 1024, 0, stream>>>(tcnt, toff, meta);
    typed_scatter_k<<<HIST_BLOCKS, 256, 0, stream>>>(ntyp, toff, perm);
    // weight prep for all layers up-front (independent of activations)
    const int douts[3] = {256, 256, 128};
    for (int l = 0; l < 3; ++l)
        cast_w_k<<<(R_REL * douts[l] * 256 + 255) / 256, 256, 0, stream>>>(
            relW[l], rootW[l], Wt[l], Rt[l], douts[l]);

    bf16* cur = h_a;
    bf16* nxt = h_b;
    for (int l = 0; l < 3; ++l) {
        int Dout = douts[l];
        int NH = Dout / 128;
        for (int h = 0; h < NH; ++h) {
            bf16* Yh = Y + (size_t)h * M_PAD * 640;
            gemm_y_k<<<dim3(M_PAD / 128, 5), 256, 0, stream>>>(
                cur, Wt[l] + (size_t)h * 640 * 256, Yh, 640);
            gather_k<<<(N_NODES + 3) / 4, 256, 0, stream>>>(
                Yh, pk, excl, Cb + h * 128, Dout);
        }
        gemm_root_k<<<dim3(393, Dout / 128), 256, 0, stream>>>(
            cur, Rt[l], rootB[l], perm, meta, Cb, C, nxt, Dout, (l < 2) ? 1 : 0);
        bf16* tmp = cur; cur = nxt; nxt = tmp;
    }
    logsoftmax_k<<<(N_NODES + 3) / 4, 256, 0, stream>>>(C, out, N_NODES);
}